// Round 5
// baseline (428.532 us; speedup 1.0000x reference)
//
#include <hip/hip_runtime.h>
#include <hip/hip_bf16.h>

// out[b,i,j,k] = sum_{p,q,r} x[b,p,q,r] W1[p,i] W2[q,j] W3[r,k]
// Stage A contracts r, B contracts q, C contracts p; each stage writes its
// result transposed in LDS so the next contracted axis is fragment-fast.
//
// R5 structure (vs R4, which was neutral at 122us vs the 121us baseline):
//  - grid-stride: 512 blocks (2/CU, all resident) x 4 rows each -> iter n's
//    stores overlap iter n+1's loads; no per-block launch/latency gaps.
//  - register prefetch: next row's 16 float4 x-loads issued right after
//    stage A, converted to bf16 at stage-B end (a full stage of latency).
//  - raw barriers: s_waitcnt lgkmcnt(0) + s_barrier + sched_barrier(0).
//    __syncthreads would drain vmcnt(0) (guide §5) and kill the pipeline;
//    LDS is the only cross-thread channel here so lgkmcnt(0) suffices.
//  - 512-thr blocks, __launch_bounds__(512,4): 128-VGPR budget holds the
//    64-reg prefetch window spill-free; each wave handles 8 m-tiles.
//  - opaque lane id per iter defeats LICM of weight loads (else 24 VGPRs
//    get pinned and stage B peaks >128 -> scratch, the R1 disaster).
//
// MFMA 16x16x32 bf16 layouts exactly as validated R3/R4 (absmax 0.036):
//   A/B lane l: k = 8*((l>>4)&3)+j ; C/D: col=l&15, row=4*((l>>4)&3)+reg.
// Wave w owns m-rows [128w,128w+128): stage A->B handoff stays wave-local
// (p in {4w..4w+3}); DS ops from one wave complete in order (R4-validated).

typedef __attribute__((ext_vector_type(8))) short bf16x8;
typedef __attribute__((ext_vector_type(4))) float f32x4;

#define NROW 32768
#define NBLK 512

// lgkmcnt(0): my DS ops retired (release/acquire for LDS). No vmcnt drain:
// prefetch loads + output stores stay in flight across the barrier (T4).
#define BAR() do {                                          \
    asm volatile("s_waitcnt lgkmcnt(0)" ::: "memory");      \
    __builtin_amdgcn_s_barrier();                           \
    __builtin_amdgcn_sched_barrier(0);                      \
} while (0)

__device__ __forceinline__ unsigned pk2(float a, float b) {
    union { __hip_bfloat162 h; unsigned u; } v;
    v.h = __float22bfloat162_rn(make_float2(a, b));        // v_cvt_pk_bf16_f32
    return v.u;
}
__device__ __forceinline__ unsigned short b16(float a) {
    union { __hip_bfloat16 h; unsigned short u; } v;
    v.h = __float2bfloat16(a);
    return v.u;
}
__device__ __forceinline__ bf16x8 packfrag(float4 f0, float4 f1) {
    union { unsigned u[4]; bf16x8 b; } r;
    r.u[0] = pk2(f0.x, f0.y); r.u[1] = pk2(f0.z, f0.w);
    r.u[2] = pk2(f1.x, f1.y); r.u[3] = pk2(f1.z, f1.w);
    return r.b;
}

// swizzled element index: 8-elem column block XOR'd by row hash -> b128-safe
__device__ __forceinline__ int swz(int row, int col) {
    int s = ((row ^ (row >> 2) ^ (row >> 4)) & 3) << 3;
    return row * 32 + (col ^ s);
}

// weight fragment: lane (c,g) holds W[k=8g+j][n=16h+c], j=0..7
__device__ __forceinline__ bf16x8 wfrag(const float* __restrict__ W, int h, int c, int g) {
    union { unsigned u[4]; bf16x8 b; } r;
#pragma unroll
    for (int jj = 0; jj < 4; ++jj) {
        float a = W[(8 * g + 2 * jj    ) * 32 + 16 * h + c];
        float b = W[(8 * g + 2 * jj + 1) * 32 + 16 * h + c];
        r.u[jj] = pk2(a, b);
    }
    return r.b;
}

// LDS fragment: row-major 32-col row, 8 contiguous cols at swizzled block
__device__ __forceinline__ bf16x8 ldsfrag(const unsigned short* buf, int row, int g) {
    int s = (row ^ (row >> 2) ^ (row >> 4)) & 3;
    union { uint4 u; bf16x8 b; } cv;
    cv.u = *(const uint4*)(buf + row * 32 + 8 * (g ^ s));
    return cv.b;
}

__global__ __launch_bounds__(512, 4) void kron3_mfma(
    const float* __restrict__ x,  const float* __restrict__ W1,
    const float* __restrict__ W2, const float* __restrict__ W3,
    float* __restrict__ out, int iters)
{
    __shared__ unsigned short buf[NROW];            // 64 KiB bf16
    const int t = threadIdx.x;
    const int w = t >> 6, c = t & 15, g = (t >> 4) & 3;
    const f32x4 vzero = {0.f, 0.f, 0.f, 0.f};

    // prologue: load + convert row 0
    float4 fr[16];
    {
        const float* xr = x + (size_t)blockIdx.x * NROW;
#pragma unroll
        for (int mt = 0; mt < 8; ++mt) {
            const float* s = xr + (128 * w + 16 * mt + c) * 32 + 8 * g;
            fr[2 * mt]     = ((const float4*)s)[0];
            fr[2 * mt + 1] = ((const float4*)s)[1];
        }
    }
    bf16x8 fa[8];
#pragma unroll
    for (int mt = 0; mt < 8; ++mt) fa[mt] = packfrag(fr[2 * mt], fr[2 * mt + 1]);

#pragma unroll 1
    for (int it = 0; it < iters; ++it) {
        // opaque lane id: weight addresses become loop-variant -> no LICM
        int tv = t;
        asm volatile("" : "+v"(tv));
        const int cv = tv & 15, gv = (tv >> 4) & 3;

        // ---- stage A: contract r.  yA[(p,k'),q] = sum_r x[(p,q),r] W3[r,k'] ----
        {
            bf16x8 wA[2] = { wfrag(W3, 0, cv, gv), wfrag(W3, 1, cv, gv) };
#pragma unroll
            for (int nt = 0; nt < 2; ++nt) {
                const int kp = 16 * nt + c;
#pragma unroll
                for (int mt = 0; mt < 8; ++mt) {
                    f32x4 a = __builtin_amdgcn_mfma_f32_16x16x32_bf16(fa[mt], wA[nt], vzero, 0, 0, 0);
                    const int p  = 4 * w + (mt >> 1);
                    const int q0 = 16 * (mt & 1) + 4 * g;
                    *(uint2*)(buf + swz(p * 32 + kp, q0)) =
                        make_uint2(pk2(a[0], a[1]), pk2(a[2], a[3]));
                }
            }
        }

        // fb: wave-local rows [128w,128w+128) -> in-wave DS ordering suffices
        bf16x8 fb[8];
#pragma unroll
        for (int mt = 0; mt < 8; ++mt)
            fb[mt] = ldsfrag(buf, 128 * w + 16 * mt + c, g);

        // prefetch next row's x: in flight across Ba + stage B (no vmcnt drain)
        if (it + 1 < iters) {
            const float* xr = x + (size_t)(blockIdx.x + NBLK * (it + 1)) * NROW;
#pragma unroll
            for (int mt = 0; mt < 8; ++mt) {
                const float* s = xr + (128 * w + 16 * mt + c) * 32 + 8 * g;
                fr[2 * mt]     = ((const float4*)s)[0];
                fr[2 * mt + 1] = ((const float4*)s)[1];
            }
        }
        BAR();   // Ba: all fb reads retired before any yB write (WAR)

        // ---- stage B: contract q.  yB[(j,k),p] = sum_q yA[(p,k),q] W2[q,j] ----
        {
            bf16x8 wB[2] = { wfrag(W2, 0, cv, gv), wfrag(W2, 1, cv, gv) };
#pragma unroll
            for (int jt = 0; jt < 2; ++jt) {
#pragma unroll
                for (int mt = 0; mt < 8; ++mt) {
                    f32x4 a = __builtin_amdgcn_mfma_f32_16x16x32_bf16(wB[jt], fb[mt], vzero, 0, 0, 0);
                    const int k = 16 * (mt & 1) + c;
                    const int p = 4 * w + (mt >> 1);
#pragma unroll
                    for (int rg = 0; rg < 4; ++rg)
                        buf[swz((16 * jt + 4 * g + rg) * 32 + k, p)] = b16(a[rg]);
                }
            }
        }
        // convert prefetched row (vmcnt covered by stage A tail + Ba + stage B)
        if (it + 1 < iters) {
#pragma unroll
            for (int mt = 0; mt < 8; ++mt) fa[mt] = packfrag(fr[2 * mt], fr[2 * mt + 1]);
        }
        BAR();   // Bb: yB writes visible (RAW)

        // ---- stage C: contract p.  out[i,j,k] = sum_p yB[(j,k),p] W1[p,i] ----
        bf16x8 fc[8];
#pragma unroll
        for (int mt = 0; mt < 8; ++mt)
            fc[mt] = ldsfrag(buf, 128 * w + 16 * mt + c, g);
        BAR();   // Bc: fc reads retired; next iter's yA writes safe (WAR)

        {
            bf16x8 wC[2] = { wfrag(W1, 0, cv, gv), wfrag(W1, 1, cv, gv) };
            float* orow = out + (size_t)(blockIdx.x + NBLK * it) * NROW;
#pragma unroll
            for (int nt = 0; nt < 2; ++nt) {
                const int i = 16 * nt + c;
#pragma unroll
                for (int mt = 0; mt < 8; ++mt) {
                    f32x4 a = __builtin_amdgcn_mfma_f32_16x16x32_bf16(fc[mt], wC[nt], vzero, 0, 0, 0);
                    const int j  = 4 * w + (mt >> 1);
                    const int k0 = 16 * (mt & 1) + 4 * g;
                    *(float4*)(orow + i * 1024 + j * 32 + k0) =
                        make_float4(a[0], a[1], a[2], a[3]);   // stores overlap next iter
                }
            }
        }
    }
}

extern "C" void kernel_launch(void* const* d_in, const int* in_sizes, int n_in,
                              void* d_out, int out_size, void* d_ws, size_t ws_size,
                              hipStream_t stream) {
    const float* x  = (const float*)d_in[0];
    const float* W1 = (const float*)d_in[1];
    const float* W2 = (const float*)d_in[2];
    const float* W3 = (const float*)d_in[3];
    float* outp = (float*)d_out;

    const int batch = in_sizes[0] / NROW;             // 2048
    const int iters = batch / NBLK;                   // 4
    kron3_mfma<<<dim3(NBLK), dim3(512), 0, stream>>>(x, W1, W2, W3, outp, iters);
}

// Round 6
// 200.814 us; speedup vs baseline: 2.1340x; 2.1340x over previous
//
#include <hip/hip_runtime.h>
#include <hip/hip_bf16.h>

// out[b,i,j,k] = sum_{p,q,r} x[b,p,q,r] W1[p,i] W2[q,j] W3[r,k]
// Stage A contracts r, B contracts q, C contracts p; each stage writes its
// result transposed in LDS so the next contracted axis is fragment-fast.
//
// R6 = R4's exact validated structure (1024 thr, maps with 0 bank conflicts,
// absmax 0.036) + grid-stride pipeline:
//  - 256 blocks x 8 rows, 1 block/CU resident for the whole kernel.
//  - __launch_bounds__(1024, 4): k = 4*4/16 = 1 block/CU -> 128-VGPR cap
//    under either reading of the 2nd arg. (R5's (512,4) resolved to a 64-VGPR
//    cap and spilled the prefetch window: WRITE 929MB, 428us. Gate: WRITE_SIZE
//    must stay ~262MB this round.)
//  - prefetch: next row's 8 float4 (32 VGPR) issued before Ba, converted to
//    bf16 after stage B (~full stage of vmcnt latency cover).
//  - raw barriers: s_waitcnt lgkmcnt(0) + s_barrier + sched_barrier(0)
//    (race-free per R5's passing run). No vmcnt drain -> prefetch loads and
//    output stores stay in flight across barriers and iterations.
//
// MFMA 16x16x32 bf16 layouts exactly as validated R3/R4:
//   A/B lane l: k = 8*((l>>4)&3)+j ; C/D: col=l&15, row=4*((l>>4)&3)+reg.
// Wave w owns m-rows [64w,64w+64); stage A->B handoff is wave-local (in-wave
// DS ordering, R4-validated). Block-wide hazards: Ba (WAR on yA), Bb (RAW on
// yB), Bc (WAR: fc reads before next iter's yA writes).

typedef __attribute__((ext_vector_type(8))) short bf16x8;
typedef __attribute__((ext_vector_type(4))) float f32x4;

#define NROW 32768
#define NBLK 256

#define BAR() do {                                          \
    asm volatile("s_waitcnt lgkmcnt(0)" ::: "memory");      \
    __builtin_amdgcn_s_barrier();                           \
    __builtin_amdgcn_sched_barrier(0);                      \
} while (0)

__device__ __forceinline__ unsigned pk2(float a, float b) {
    union { __hip_bfloat162 h; unsigned u; } v;
    v.h = __float22bfloat162_rn(make_float2(a, b));        // v_cvt_pk_bf16_f32
    return v.u;
}
__device__ __forceinline__ unsigned short b16(float a) {
    union { __hip_bfloat16 h; unsigned short u; } v;
    v.h = __float2bfloat16(a);
    return v.u;
}
__device__ __forceinline__ bf16x8 packfrag(float4 f0, float4 f1) {
    union { unsigned u[4]; bf16x8 b; } r;
    r.u[0] = pk2(f0.x, f0.y); r.u[1] = pk2(f0.z, f0.w);
    r.u[2] = pk2(f1.x, f1.y); r.u[3] = pk2(f1.z, f1.w);
    return r.b;
}

// swizzled element index: 8-elem column block XOR'd by row hash -> b128-safe
__device__ __forceinline__ int swz(int row, int col) {
    int s = ((row ^ (row >> 2) ^ (row >> 4)) & 3) << 3;
    return row * 32 + (col ^ s);
}

// weight fragment: lane (c,g) holds W[k=8g+j][n=16h+c], j=0..7
__device__ __forceinline__ bf16x8 wfrag(const float* __restrict__ W, int h, int c, int g) {
    union { unsigned u[4]; bf16x8 b; } r;
#pragma unroll
    for (int jj = 0; jj < 4; ++jj) {
        float a = W[(8 * g + 2 * jj    ) * 32 + 16 * h + c];
        float b = W[(8 * g + 2 * jj + 1) * 32 + 16 * h + c];
        r.u[jj] = pk2(a, b);
    }
    return r.b;
}

// LDS fragment: row-major 32-col row, 8 contiguous cols at swizzled block
__device__ __forceinline__ bf16x8 ldsfrag(const unsigned short* buf, int row, int g) {
    int s = (row ^ (row >> 2) ^ (row >> 4)) & 3;
    union { uint4 u; bf16x8 b; } cv;
    cv.u = *(const uint4*)(buf + row * 32 + 8 * (g ^ s));
    return cv.b;
}

__global__ __launch_bounds__(1024, 4) void kron3_mfma(
    const float* __restrict__ x,  const float* __restrict__ W1,
    const float* __restrict__ W2, const float* __restrict__ W3,
    float* __restrict__ out, int iters)
{
    __shared__ unsigned short buf[NROW];            // 64 KiB bf16
    const int t = threadIdx.x;
    const int w = t >> 6, c = t & 15, g = (t >> 4) & 3;
    const f32x4 vzero = {0.f, 0.f, 0.f, 0.f};

    // prologue: load + convert row 0 (R4 map: wave w rows [64w,64w+64))
    float4 fr[8];
    {
        const float* xr = x + (size_t)blockIdx.x * NROW;
#pragma unroll
        for (int mt = 0; mt < 4; ++mt) {
            const float* s = xr + (64 * w + 16 * mt + c) * 32 + 8 * g;
            fr[2 * mt]     = ((const float4*)s)[0];
            fr[2 * mt + 1] = ((const float4*)s)[1];
        }
    }
    bf16x8 fa[4];
#pragma unroll
    for (int mt = 0; mt < 4; ++mt) fa[mt] = packfrag(fr[2 * mt], fr[2 * mt + 1]);

#pragma unroll 1
    for (int it = 0; it < iters; ++it) {
        // opaque lane id: weight addresses loop-variant -> no LICM pinning
        int tv = t;
        asm volatile("" : "+v"(tv));
        const int cv = tv & 15, gv = (tv >> 4) & 3;

        // ---- stage A: contract r.  yA[(p,k'),q] = sum_r x[(p,q),r] W3[r,k'] ----
        {
            bf16x8 wA[2] = { wfrag(W3, 0, cv, gv), wfrag(W3, 1, cv, gv) };
#pragma unroll
            for (int nt = 0; nt < 2; ++nt) {
                const int kp = 16 * nt + c;
#pragma unroll
                for (int mt = 0; mt < 4; ++mt) {
                    f32x4 a = __builtin_amdgcn_mfma_f32_16x16x32_bf16(fa[mt], wA[nt], vzero, 0, 0, 0);
                    const int p  = 2 * w + (mt >> 1);
                    const int q0 = 16 * (mt & 1) + 4 * g;
                    *(uint2*)(buf + swz(p * 32 + kp, q0)) =
                        make_uint2(pk2(a[0], a[1]), pk2(a[2], a[3]));
                }
            }
        }

        // fb: wave-local rows [64w,64w+64) -> in-wave DS ordering suffices
        bf16x8 fb[4];
#pragma unroll
        for (int mt = 0; mt < 4; ++mt)
            fb[mt] = ldsfrag(buf, 64 * w + 16 * mt + c, g);

        // prefetch next row's x (32 VGPR window); in flight across Ba+stage B
        if (it + 1 < iters) {
            const float* xr = x + (size_t)(blockIdx.x + NBLK * (it + 1)) * NROW;
#pragma unroll
            for (int mt = 0; mt < 4; ++mt) {
                const float* s = xr + (64 * w + 16 * mt + c) * 32 + 8 * g;
                fr[2 * mt]     = ((const float4*)s)[0];
                fr[2 * mt + 1] = ((const float4*)s)[1];
            }
        }
        BAR();   // Ba: all fb reads retired before any yB write (WAR)

        // ---- stage B: contract q.  yB[(j,k),p] = sum_q yA[(p,k),q] W2[q,j] ----
        {
            bf16x8 wB[2] = { wfrag(W2, 0, cv, gv), wfrag(W2, 1, cv, gv) };
#pragma unroll
            for (int jt = 0; jt < 2; ++jt) {
#pragma unroll
                for (int mt = 0; mt < 4; ++mt) {
                    f32x4 a = __builtin_amdgcn_mfma_f32_16x16x32_bf16(wB[jt], fb[mt], vzero, 0, 0, 0);
                    const int k = 16 * (mt & 1) + c;
                    const int p = 2 * w + (mt >> 1);
#pragma unroll
                    for (int rg = 0; rg < 4; ++rg)
                        buf[swz((16 * jt + 4 * g + rg) * 32 + k, p)] = b16(a[rg]);
                }
            }
        }
        // convert prefetched row (vmcnt covered by Ba + stage B)
        if (it + 1 < iters) {
#pragma unroll
            for (int mt = 0; mt < 4; ++mt) fa[mt] = packfrag(fr[2 * mt], fr[2 * mt + 1]);
        }
        BAR();   // Bb: yB writes visible (RAW)

        // ---- stage C: contract p.  out[i,j,k] = sum_p yB[(j,k),p] W1[p,i] ----
        bf16x8 fc[4];
#pragma unroll
        for (int mt = 0; mt < 4; ++mt)
            fc[mt] = ldsfrag(buf, 64 * w + 16 * mt + c, g);
        BAR();   // Bc: fc reads retired; next iter's yA writes safe (WAR)

        {
            bf16x8 wC[2] = { wfrag(W1, 0, cv, gv), wfrag(W1, 1, cv, gv) };
            float* orow = out + (size_t)(blockIdx.x + NBLK * it) * NROW;
#pragma unroll
            for (int nt = 0; nt < 2; ++nt) {
                const int i = 16 * nt + c;
#pragma unroll
                for (int mt = 0; mt < 4; ++mt) {
                    f32x4 a = __builtin_amdgcn_mfma_f32_16x16x32_bf16(fc[mt], wC[nt], vzero, 0, 0, 0);
                    const int j  = 2 * w + (mt >> 1);
                    const int k0 = 16 * (mt & 1) + 4 * g;
                    *(float4*)(orow + i * 1024 + j * 32 + k0) =
                        make_float4(a[0], a[1], a[2], a[3]);   // overlap next iter
                }
            }
        }
    }
}

extern "C" void kernel_launch(void* const* d_in, const int* in_sizes, int n_in,
                              void* d_out, int out_size, void* d_ws, size_t ws_size,
                              hipStream_t stream) {
    const float* x  = (const float*)d_in[0];
    const float* W1 = (const float*)d_in[1];
    const float* W2 = (const float*)d_in[2];
    const float* W3 = (const float*)d_in[3];
    float* outp = (float*)d_out;

    const int batch = in_sizes[0] / NROW;             // 2048
    const int iters = batch / NBLK;                   // 8
    kron3_mfma<<<dim3(NBLK), dim3(1024), 0, stream>>>(x, W1, W2, W3, outp, iters);
}

// Round 7
// 149.584 us; speedup vs baseline: 2.8648x; 1.3425x over previous
//
#include <hip/hip_runtime.h>
#include <hip/hip_bf16.h>

// out[b,i,j,k] = sum_{p,q,r} x[b,p,q,r] W1[p,i] W2[q,j] W3[r,k]
// Stage A contracts r, B contracts q, C contracts p; each stage writes its
// result transposed in LDS so the next contracted axis is fragment-fast.
//
// R7 = R4's exact validated compute structure (1024 thr, maps absmax 0.036)
// with two changes, each fixing a measured R5/R6 failure:
//  - __launch_bounds__(1024, 8): caps VGPR at 64 under BOTH readings of the
//    2nd arg (this hipcc empirically reads it CUDA-style min-blocks/CU:
//    (512,4)->64cap, (1024,4)->64cap, both spilled). R3/R4 shipped (1024,8)
//    spill-free. NO register prefetch this round - that's what spilled.
//  - persistent grid: 512 blocks = 2 resident blocks/CU x 4 rows grid-stride.
//    R6's 256-block version had 1 block/CU: barrier stalls had no cover
//    (Occupancy 45%, VALUBusy 8%). Two co-resident blocks interleave:
//    one computes while the other waits on loads/barriers.
//  - weights staged ONCE to LDS as W^T bf16 (6KB, swizzled): per-iter weight
//    cost 48 global loads + 24 cvt -> 6 ds_read_b128, no pinned registers
//    (opaque lane id keeps fragment reads loop-variant, LICM-proof).
// Raw barriers (lgkmcnt(0)+s_barrier+sched_barrier(0), NO vmcnt drain) are
// R5/R6-validated race-free; output stores + x loads stay in flight across
// barriers and iterations.
//
// MFMA 16x16x32 bf16 layouts exactly as validated R3/R4:
//   A/B lane l: k = 8*((l>>4)&3)+j ; C/D: col=l&15, row=4*((l>>4)&3)+reg.
// Wave w owns m-rows [64w,64w+64); stage A->B handoff is wave-local (in-wave
// DS ordering). Block-wide hazards: Ba (WAR on yA), Bb (RAW on yB), Bc (WAR:
// fc reads before next iter's stage-A writes).

typedef __attribute__((ext_vector_type(8))) short bf16x8;
typedef __attribute__((ext_vector_type(4))) float f32x4;

#define NROW 32768
#define NBLK 512

#define BAR() do {                                          \
    asm volatile("s_waitcnt lgkmcnt(0)" ::: "memory");      \
    __builtin_amdgcn_s_barrier();                           \
    __builtin_amdgcn_sched_barrier(0);                      \
} while (0)

__device__ __forceinline__ unsigned pk2(float a, float b) {
    union { __hip_bfloat162 h; unsigned u; } v;
    v.h = __float22bfloat162_rn(make_float2(a, b));        // v_cvt_pk_bf16_f32
    return v.u;
}
__device__ __forceinline__ unsigned short b16(float a) {
    union { __hip_bfloat16 h; unsigned short u; } v;
    v.h = __float2bfloat16(a);
    return v.u;
}
__device__ __forceinline__ bf16x8 packfrag(float4 f0, float4 f1) {
    union { unsigned u[4]; bf16x8 b; } r;
    r.u[0] = pk2(f0.x, f0.y); r.u[1] = pk2(f0.z, f0.w);
    r.u[2] = pk2(f1.x, f1.y); r.u[3] = pk2(f1.z, f1.w);
    return r.b;
}

// swizzled element index: 8-elem column block XOR'd by row hash -> b128-safe
__device__ __forceinline__ int swz(int row, int col) {
    int s = ((row ^ (row >> 2) ^ (row >> 4)) & 3) << 3;
    return row * 32 + (col ^ s);
}

// LDS fragment: row-major 32-col row, 8 contiguous cols at swizzled block
__device__ __forceinline__ bf16x8 ldsfrag(const unsigned short* buf, int row, int g) {
    int s = (row ^ (row >> 2) ^ (row >> 4)) & 3;
    union { uint4 u; bf16x8 b; } cv;
    cv.u = *(const uint4*)(buf + row * 32 + 8 * (g ^ s));
    return cv.b;
}

__global__ __launch_bounds__(1024, 8) void kron3_mfma(
    const float* __restrict__ x,  const float* __restrict__ W1,
    const float* __restrict__ W2, const float* __restrict__ W3,
    float* __restrict__ out, int iters)
{
    __shared__ unsigned short buf[NROW];       // 64 KiB bf16 row workspace
    __shared__ unsigned short wlds[3 * 1024];  // 6 KiB: W1^T,W2^T,W3^T bf16
    const int t = threadIdx.x;
    const int w = t >> 6, c = t & 15, g = (t >> 4) & 3;
    const f32x4 vzero = {0.f, 0.f, 0.f, 0.f};

    // ---- stage weights once: wlds[m][n][k] = Wm[k][n]  (swizzled bf16) ----
    {
        const int n = t >> 5, k = t & 31;
        wlds[0 * 1024 + swz(n, k)] = b16(W1[k * 32 + n]);
        wlds[1 * 1024 + swz(n, k)] = b16(W2[k * 32 + n]);
        wlds[2 * 1024 + swz(n, k)] = b16(W3[k * 32 + n]);
    }
    BAR();

#pragma unroll 1
    for (int it = 0; it < iters; ++it) {
        // opaque lane id: weight-fragment LDS addrs loop-variant -> no LICM
        int tv = t;
        asm volatile("" : "+v"(tv));
        const int cv = tv & 15, gv = (tv >> 4) & 3;
        const size_t row = (size_t)blockIdx.x + (size_t)NBLK * it;

        // ---- fa: direct from global (rows mA=(p,q), k=r), coalesced ----
        bf16x8 fa[4];
        {
            const float* xr = x + row * NROW;
#pragma unroll
            for (int mt = 0; mt < 4; ++mt) {
                const float* s = xr + (64 * w + 16 * mt + c) * 32 + 8 * g;
                float4 f0 = ((const float4*)s)[0];
                float4 f1 = ((const float4*)s)[1];
                fa[mt] = packfrag(f0, f1);
            }
        }

        // ---- stage A: contract r.  yA[(p,k'),q] = sum_r x[(p,q),r] W3[r,k'] ----
        {
            bf16x8 wA0 = ldsfrag(wlds + 2048, cv, gv);        // W3^T rows n=k'
            bf16x8 wA1 = ldsfrag(wlds + 2048, 16 + cv, gv);
#pragma unroll
            for (int nt = 0; nt < 2; ++nt) {
                const int kp = 16 * nt + c;
                const bf16x8 wA = nt ? wA1 : wA0;
#pragma unroll
                for (int mt = 0; mt < 4; ++mt) {
                    f32x4 a = __builtin_amdgcn_mfma_f32_16x16x32_bf16(fa[mt], wA, vzero, 0, 0, 0);
                    const int p  = 2 * w + (mt >> 1);
                    const int q0 = 16 * (mt & 1) + 4 * g;
                    *(uint2*)(buf + swz(p * 32 + kp, q0)) =
                        make_uint2(pk2(a[0], a[1]), pk2(a[2], a[3]));
                }
            }
        }

        // fb: wave-local rows [64w,64w+64) -> in-wave DS ordering suffices
        bf16x8 fb[4];
#pragma unroll
        for (int mt = 0; mt < 4; ++mt)
            fb[mt] = ldsfrag(buf, 64 * w + 16 * mt + c, g);
        BAR();   // Ba: all fb reads retired before any yB write (WAR)

        // ---- stage B: contract q.  yB[(j,k),p] = sum_q yA[(p,k),q] W2[q,j] ----
        {
            bf16x8 wB0 = ldsfrag(wlds + 1024, cv, gv);        // W2^T rows n=j
            bf16x8 wB1 = ldsfrag(wlds + 1024, 16 + cv, gv);
#pragma unroll
            for (int jt = 0; jt < 2; ++jt) {
                const bf16x8 wB = jt ? wB1 : wB0;
#pragma unroll
                for (int mt = 0; mt < 4; ++mt) {
                    f32x4 a = __builtin_amdgcn_mfma_f32_16x16x32_bf16(wB, fb[mt], vzero, 0, 0, 0);
                    const int k = 16 * (mt & 1) + c;
                    const int p = 2 * w + (mt >> 1);
#pragma unroll
                    for (int rg = 0; rg < 4; ++rg)
                        buf[swz((16 * jt + 4 * g + rg) * 32 + k, p)] = b16(a[rg]);
                }
            }
        }
        BAR();   // Bb: yB writes visible (RAW)

        // ---- stage C: contract p.  out[i,j,k] = sum_p yB[(j,k),p] W1[p,i] ----
        bf16x8 fc[4];
#pragma unroll
        for (int mt = 0; mt < 4; ++mt)
            fc[mt] = ldsfrag(buf, 64 * w + 16 * mt + c, g);
        BAR();   // Bc: fc reads retired; next iter's yA writes safe (WAR)

        {
            bf16x8 wC0 = ldsfrag(wlds, cv, gv);               // W1^T rows n=i
            bf16x8 wC1 = ldsfrag(wlds, 16 + cv, gv);
            float* orow = out + row * NROW;
#pragma unroll
            for (int nt = 0; nt < 2; ++nt) {
                const int i = 16 * nt + c;
                const bf16x8 wC = nt ? wC1 : wC0;
#pragma unroll
                for (int mt = 0; mt < 4; ++mt) {
                    f32x4 a = __builtin_amdgcn_mfma_f32_16x16x32_bf16(fc[mt], wC, vzero, 0, 0, 0);
                    const int j  = 2 * w + (mt >> 1);
                    const int k0 = 16 * (mt & 1) + 4 * g;
                    *(float4*)(orow + i * 1024 + j * 32 + k0) =
                        make_float4(a[0], a[1], a[2], a[3]);   // in flight across iters
                }
            }
        }
    }
}

extern "C" void kernel_launch(void* const* d_in, const int* in_sizes, int n_in,
                              void* d_out, int out_size, void* d_ws, size_t ws_size,
                              hipStream_t stream) {
    const float* x  = (const float*)d_in[0];
    const float* W1 = (const float*)d_in[1];
    const float* W2 = (const float*)d_in[2];
    const float* W3 = (const float*)d_in[3];
    float* outp = (float*)d_out;

    const int batch = in_sizes[0] / NROW;             // 2048
    const int iters = batch / NBLK;                   // 4
    kron3_mfma<<<dim3(NBLK), dim3(1024), 0, stream>>>(x, W1, W2, W3, outp, iters);
}

// Round 9
// 121.178 us; speedup vs baseline: 3.5364x; 1.2344x over previous
//
#include <hip/hip_runtime.h>
#include <hip/hip_bf16.h>

// out[b,i,j,k] = sum_{p,q,r} x[b,p,q,r] W1[p,i] W2[q,j] W3[r,k]
// Stage A contracts r, B contracts q, C contracts p.
//
// R9 = R8 with the compile fix: nontemporal store through clang ext-vector
// f32x4 (HIP float4 is a class type -> rejected by the builtin).
//
// Structural change vs R4 (proven 122.7us): intermediate layouts chosen so
// stage-B writes are PACKED b64 instead of 32 scalar b16/wave at 8-way
// conflict (8.4M conflict cycles, ~65% of LDS-pipe demand, co-critical with
// HBM per the R7 post-mortem):
//   yA : buf[(k'*32+p)][q]  (p in m-low bits -> stage-B D regs = consecutive p)
//   yB : buf[(j*32+k')][p]  (stage-C b128 fragment reads, k-dim = p)
// Stage B uses fb as A-operand (un-swapped). Index algebra re-derived against
// the m89-verified mappings:
//   A/B lane l: row/col = l&15, k = 8*((l>>4)&3)+j ; C/D: col=l&15 (n),
//   row-in-tile = 4*((l>>4)&3)+reg (m).
// Cost: stage-A writes are cross-wave now -> 3 __syncthreads (R3's 5 vs R4's
// 2 measured equal; barrier count is not the lever here).
// Output stores nontemporal (out never re-read; keep L2/L3 for x).

typedef __attribute__((ext_vector_type(8))) short bf16x8;
typedef __attribute__((ext_vector_type(4))) float f32x4;

#define NROW 32768

__device__ __forceinline__ unsigned pk2(float a, float b) {
    union { __hip_bfloat162 h; unsigned u; } v;
    v.h = __float22bfloat162_rn(make_float2(a, b));        // v_cvt_pk_bf16_f32
    return v.u;
}
__device__ __forceinline__ bf16x8 packfrag(float4 f0, float4 f1) {
    union { unsigned u[4]; bf16x8 b; } r;
    r.u[0] = pk2(f0.x, f0.y); r.u[1] = pk2(f0.z, f0.w);
    r.u[2] = pk2(f1.x, f1.y); r.u[3] = pk2(f1.z, f1.w);
    return r.b;
}

// swizzled element index: 8-elem column block XOR'd by row hash (b128-safe;
// 4-aligned sub-blocks survive: s only flips bits 3..4 of the column)
__device__ __forceinline__ int swz(int row, int col) {
    int s = ((row ^ (row >> 2) ^ (row >> 4)) & 3) << 3;
    return row * 32 + (col ^ s);
}

// weight fragment: lane (c,g) holds W[k=8g+j][n=16h+c], j=0..7 (k-consecutive)
__device__ __forceinline__ bf16x8 wfrag(const float* __restrict__ W, int h, int c, int g) {
    union { unsigned u[4]; bf16x8 b; } r;
#pragma unroll
    for (int jj = 0; jj < 4; ++jj) {
        float a = W[(8 * g + 2 * jj    ) * 32 + 16 * h + c];
        float b = W[(8 * g + 2 * jj + 1) * 32 + 16 * h + c];
        r.u[jj] = pk2(a, b);
    }
    return r.b;
}

// LDS fragment: row-major 32-col row, 8 contiguous cols at swizzled block
__device__ __forceinline__ bf16x8 ldsfrag(const unsigned short* buf, int row, int g) {
    int s = (row ^ (row >> 2) ^ (row >> 4)) & 3;
    union { uint4 u; bf16x8 b; } cv;
    cv.u = *(const uint4*)(buf + row * 32 + 8 * (g ^ s));
    return cv.b;
}

__global__ __launch_bounds__(1024, 8) void kron3_mfma(
    const float* __restrict__ x,  const float* __restrict__ W1,
    const float* __restrict__ W2, const float* __restrict__ W3,
    float* __restrict__ out)
{
    __shared__ unsigned short buf[NROW];            // 64 KiB bf16
    const int t = threadIdx.x;
    const int w = t >> 6, c = t & 15, g = (t >> 4) & 3;
    const float* __restrict__ xrow = x + (size_t)blockIdx.x * NROW;
    float* __restrict__ orow = out + (size_t)blockIdx.x * NROW;
    const f32x4 vzero = {0.f, 0.f, 0.f, 0.f};

    // ---- stage-A A-fragments straight from global (rows mA=(p,q), k=r) ----
    bf16x8 fa[4];
#pragma unroll
    for (int mt = 0; mt < 4; ++mt) {
        const float* s = xrow + (64 * w + 16 * mt + c) * 32 + 8 * g;
        float4 f0 = ((const float4*)s)[0];
        float4 f1 = ((const float4*)s)[1];
        fa[mt] = packfrag(f0, f1);
    }
    bf16x8 wA[2] = { wfrag(W3, 0, c, g), wfrag(W3, 1, c, g) };

    // ---- stage A: contract r.  yA[(k',p)][q] = sum_r x[(p,q),r] W3[r,k'] ----
    // D lane (c,g) reg rg: p=2w+(mt>>1), q=16(mt&1)+4g+rg, k'=16nt+c
#pragma unroll
    for (int nt = 0; nt < 2; ++nt) {
        const int kp = 16 * nt + c;
#pragma unroll
        for (int mt = 0; mt < 4; ++mt) {
            f32x4 a = __builtin_amdgcn_mfma_f32_16x16x32_bf16(fa[mt], wA[nt], vzero, 0, 0, 0);
            const int p  = 2 * w + (mt >> 1);
            const int q0 = 16 * (mt & 1) + 4 * g;
            *(uint2*)(buf + swz(kp * 32 + p, q0)) =
                make_uint2(pk2(a[0], a[1]), pk2(a[2], a[3]));   // packed b64
        }
    }
    __syncthreads();   // S1: yA complete (RAW; stage-A writes are cross-wave)

    // ---- stage B fragments: A-operand rows m'=(k',p), k-dim = q ----
    bf16x8 fb[4];
#pragma unroll
    for (int mt = 0; mt < 4; ++mt)
        fb[mt] = ldsfrag(buf, 64 * w + 16 * mt + c, g);
    bf16x8 wB[2] = { wfrag(W2, 0, c, g), wfrag(W2, 1, c, g) };
    __syncthreads();   // S2: all yA reads retired before yB overwrites (WAR)

    // ---- stage B: contract q.  yB[(j,k')][p] = sum_q yA[(k',p)][q] W2[q,j] ----
    // D lane (c,g) reg rg: k'=2w+(mt>>1), p=16(mt&1)+4g+rg (consecutive!), j=16nt+c
#pragma unroll
    for (int nt = 0; nt < 2; ++nt) {
        const int j = 16 * nt + c;
#pragma unroll
        for (int mt = 0; mt < 4; ++mt) {
            f32x4 a = __builtin_amdgcn_mfma_f32_16x16x32_bf16(fb[mt], wB[nt], vzero, 0, 0, 0);
            const int kq = 2 * w + (mt >> 1);
            const int p0 = 16 * (mt & 1) + 4 * g;
            *(uint2*)(buf + swz(j * 32 + kq, p0)) =
                make_uint2(pk2(a[0], a[1]), pk2(a[2], a[3]));   // packed b64
        }
    }
    __syncthreads();   // S3: yB complete (RAW)

    // ---- stage C: contract p.  out[i,j,k] = sum_p yB[(j,k)][p] W1[p,i] ----
    bf16x8 fc[4];
#pragma unroll
    for (int mt = 0; mt < 4; ++mt)
        fc[mt] = ldsfrag(buf, 64 * w + 16 * mt + c, g);   // rows (j,k), k-dim p
    bf16x8 wC[2] = { wfrag(W1, 0, c, g), wfrag(W1, 1, c, g) };

#pragma unroll
    for (int nt = 0; nt < 2; ++nt) {
        const int i = 16 * nt + c;
#pragma unroll
        for (int mt = 0; mt < 4; ++mt) {
            f32x4 a = __builtin_amdgcn_mfma_f32_16x16x32_bf16(fc[mt], wC[nt], vzero, 0, 0, 0);
            const int j  = 2 * w + (mt >> 1);
            const int k0 = 16 * (mt & 1) + 4 * g;
            __builtin_nontemporal_store(a,
                (f32x4*)(orow + i * 1024 + j * 32 + k0));   // out never re-read
        }
    }
}

extern "C" void kernel_launch(void* const* d_in, const int* in_sizes, int n_in,
                              void* d_out, int out_size, void* d_ws, size_t ws_size,
                              hipStream_t stream) {
    const float* x  = (const float*)d_in[0];
    const float* W1 = (const float*)d_in[1];
    const float* W2 = (const float*)d_in[2];
    const float* W3 = (const float*)d_in[3];
    float* outp = (float*)d_out;

    const int batch = in_sizes[0] / NROW;             // 2048
    kron3_mfma<<<dim3(batch), dim3(1024), 0, stream>>>(x, W1, W2, W3, outp);
}